// Round 1
// baseline (1325.692 us; speedup 1.0000x reference)
//
#include <hip/hip_runtime.h>

// ----------------------------------------------------------------------------
// S4 block: y = GELU( irfft(rfft(u,2L) * (rfft(k,2L) + D)) [:L] ) ; out = W@y + b
// B=8, C=1, H=512, L=8192, N=2L=16384
//
// FFT: four-step register-resident factorization 16384 = 16*16*16*4.
//   1024 threads, 16 complex points/thread in VGPRs. 16-point DFTs with
//   hard-coded twiddles. LDS restructured to 71,680 B (vs 139 KB) so TWO
//   blocks co-reside per CU (32 waves):
//     - exchange A (cross-wave transpose): 2 column-rounds through an
//       8192-float2 buffer (+tmp[8] staging for not-yet-dumped waves)
//     - exchanges B/C are intra-wave: per-wave private 560-float2 slices,
//       ordered by s_waitcnt lgkmcnt(0) only -- NO block barriers.
//   Inverse is the exact mirror. Scrambled bin order sigma is shared by
//   kf_build and conv_gelu, so the pointwise product is order-consistent.
// ----------------------------------------------------------------------------

typedef unsigned short ushort_t;
typedef __bf16 bf16x8 __attribute__((ext_vector_type(8)));
typedef float  f32x4  __attribute__((ext_vector_type(4)));

#define TWO_PI 6.283185307179586f
#define LGKM() asm volatile("s_waitcnt lgkmcnt(0)" ::: "memory")

__device__ __forceinline__ float2 cmulf(float2 a, float2 b) {
    return make_float2(a.x * b.x - a.y * b.y, a.x * b.y + a.y * b.x);
}
__device__ __forceinline__ float2 caddf(float2 a, float2 b) { return make_float2(a.x + b.x, a.y + b.y); }
__device__ __forceinline__ float2 csubf(float2 a, float2 b) { return make_float2(a.x - b.x, a.y - b.y); }

__device__ __forceinline__ ushort_t f2bf(float f) {
    unsigned int u = __float_as_uint(f);
    u = (u + 0x7fffu + ((u >> 16) & 1u)) >> 16;
    return (ushort_t)u;
}

__device__ __forceinline__ float gelu_exact(float x) {
    return 0.5f * x * (1.0f + erff(x * 0.70710678118654752f));
}

// ---------------- 4-point DFT, natural in/out (INV = conjugate kernel) ------
template<bool INV>
__device__ __forceinline__ void dft4(float2& x0, float2& x1, float2& x2, float2& x3) {
    float2 t0 = caddf(x0, x2), t1 = csubf(x0, x2);
    float2 t2 = caddf(x1, x3), t3 = csubf(x1, x3);
    x0 = caddf(t0, t2);
    x2 = csubf(t0, t2);
    if (!INV) {
        x1 = make_float2(t1.x + t3.y, t1.y - t3.x);   // t1 - i*t3
        x3 = make_float2(t1.x - t3.y, t1.y + t3.x);   // t1 + i*t3
    } else {
        x1 = make_float2(t1.x - t3.y, t1.y + t3.x);
        x3 = make_float2(t1.x + t3.y, t1.y - t3.x);
    }
}

// multiply by twiddle (wr, wi); INV conjugates the twiddle
template<bool INV>
__device__ __forceinline__ float2 cmulc(float2 a, float wr, float wi) {
    float i2 = INV ? -wi : wi;
    return make_float2(a.x * wr - a.y * i2, a.x * i2 + a.y * wr);
}

#define C1_ 0.9238795325112867f
#define S1_ 0.3826834323650898f
#define R2_ 0.7071067811865476f

// ---------------- 16-point DFT, natural in/out ------------------------------
// four-step 16 = 4x4: n = 4a+b, k = c+4e.
// HZ: inputs r[8..15] are known-zero (skip half the inner butterflies).
template<bool INV, bool HZ>
__device__ __forceinline__ void dft16(float2* r) {
#pragma unroll
    for (int b = 0; b < 4; ++b) {
        if (HZ) {
            float2 u = r[b], v = r[4 + b];
            r[b]     = caddf(u, v);
            r[8 + b] = csubf(u, v);
            if (!INV) { r[4 + b]  = make_float2(u.x + v.y, u.y - v.x);
                        r[12 + b] = make_float2(u.x - v.y, u.y + v.x); }
            else      { r[4 + b]  = make_float2(u.x - v.y, u.y + v.x);
                        r[12 + b] = make_float2(u.x + v.y, u.y - v.x); }
        } else {
            dft4<INV>(r[b], r[4 + b], r[8 + b], r[12 + b]);
        }
    }
    // twiddle r[4c+b] *= w16^{bc}
    r[5]  = cmulc<INV>(r[5],  C1_, -S1_);   // w^1
    r[6]  = cmulc<INV>(r[6],  R2_, -R2_);   // w^2
    r[7]  = cmulc<INV>(r[7],  S1_, -C1_);   // w^3
    r[9]  = cmulc<INV>(r[9],  R2_, -R2_);   // w^2
    r[10] = cmulc<INV>(r[10], 0.f, -1.f);   // w^4
    r[11] = cmulc<INV>(r[11], -R2_, -R2_);  // w^6
    r[13] = cmulc<INV>(r[13], S1_, -C1_);   // w^3
    r[14] = cmulc<INV>(r[14], -R2_, -R2_);  // w^6
    r[15] = cmulc<INV>(r[15], -C1_,  S1_);  // w^9
    float2 o[16];
#pragma unroll
    for (int c = 0; c < 4; ++c) {
        float2 a0 = r[4*c], a1 = r[4*c+1], a2 = r[4*c+2], a3 = r[4*c+3];
        dft4<INV>(a0, a1, a2, a3);
        o[c] = a0; o[c + 4] = a1; o[c + 8] = a2; o[c + 12] = a3;
    }
#pragma unroll
    for (int i = 0; i < 16; ++i) r[i] = o[i];
}

// apply w^k, w = e^{i*theta}, to x[1..15] (x[0] *= w^0)
__device__ __forceinline__ void twiddle_apply(float2* x, float theta) {
    float s, c;
    __sincosf(theta, &s, &c);
    float2 w = make_float2(c, s), wk = w;
#pragma unroll
    for (int k = 1; k < 16; ++k) { x[k] = cmulf(x[k], wk); wk = cmulf(wk, w); }
}

// ----------------------------------------------------------------------------
// Shared scratch: 8960 float2 = 71,680 B  -> 2 blocks/CU.
//   [0, 8192)        : exchange-A / exchange-BA' half-signal buffer
//   SH + w*560       : wave-private slice for exchanges B, C (and mirrors)
// ----------------------------------------------------------------------------
#define SH_SIZE 8960
#define PW_STRIDE 560

// ---------------- forward: regs(natural a-chunks) -> regs(sigma bins) -------
// thread t holds x[a] = in[a*1024 + t] (a=8..15 zero). Output: 16 sigma-bins.
__device__ __forceinline__ void fft_fwd(float2* x, float2* SH, int t) {
    const int w  = t >> 6;          // wave / k1
    const int d  = t & 63;
    const int kb = (t >> 2) & 15;
    const int f  = t & 3;
    float2* PW = SH + w * PW_STRIDE;
    float2 tmp[8];
    const bool tlo = (t < 512);

    // phase A: DFT16 over a (half-zero) + twiddle w_N^t
    dft16<false, true>(x);
    twiddle_apply(x, -TWO_PI * (float)t * (1.0f / 16384.0f));

    // ---- exchange A: logical pos p = r*1024 + t' ; read p = w*1024 + c*64 + d
    // col-split rounds through SH[0..8191], slot = r*512 + (t' & 511)
    if (tlo) {
#pragma unroll
        for (int r = 0; r < 16; ++r) SH[r * 512 + t] = x[r];
    }
    __syncthreads();
#pragma unroll
    for (int c = 0; c < 8; ++c) {
        float2 v = SH[w * 512 + c * 64 + d];
        if (tlo) x[c] = v; else tmp[c] = v;
    }
    __syncthreads();
    if (!tlo) {
#pragma unroll
        for (int r = 0; r < 16; ++r) SH[r * 512 + (t - 512)] = x[r];
    }
    __syncthreads();
#pragma unroll
    for (int c = 8; c < 16; ++c) x[c] = SH[w * 512 + (c - 8) * 64 + d];
    if (!tlo) {
#pragma unroll
        for (int c = 0; c < 8; ++c) x[c] = tmp[c];
    }

    // phase B: DFT16 over c + twiddle w_1024^d
    dft16<false, false>(x);
    twiddle_apply(x, -TWO_PI * (float)d * (1.0f / 1024.0f));
    __syncthreads();   // all waves done reading SH[0..8191]; private slices now safe

    // ---- exchange B (intra-wave): write row r col d, read row kb col e*4+f
    // col-split by d; per-wave slot = r*33 + (d & 31); NO barriers.
    {
        const bool dlo = (d < 32);
        const int dc = d & 31;
        if (dlo) {
#pragma unroll
            for (int r = 0; r < 16; ++r) PW[r * 33 + dc] = x[r];
        }
        LGKM();
#pragma unroll
        for (int e = 0; e < 8; ++e) {
            float2 v = PW[kb * 33 + e * 4 + f];
            if (dlo) x[e] = v; else tmp[e] = v;
        }
        LGKM();
        if (!dlo) {
#pragma unroll
            for (int r = 0; r < 16; ++r) PW[r * 33 + dc] = x[r];
        }
        LGKM();
#pragma unroll
        for (int e = 8; e < 16; ++e) x[e] = PW[kb * 33 + (e - 8) * 4 + f];
        if (!dlo) {
#pragma unroll
            for (int e = 0; e < 8; ++e) x[e] = tmp[e];
        }
    }

    // phase C: DFT16 over e + twiddle w_64^f
    dft16<false, false>(x);
    twiddle_apply(x, -TWO_PI * (float)f * (1.0f / 64.0f));

    // ---- exchange C (intra-wave, kb-diagonal): half-wave sequential rounds
    // slot = (kb&7)*66 + col; write col = r*4+f, read col = f*16 + q*4 + ff
    {
        const int row = (kb & 7) * 66;
        const bool klo = (kb < 8);
        if (klo) {
#pragma unroll
            for (int r = 0; r < 16; ++r) PW[row + r * 4 + f] = x[r];
        }
        LGKM();
        if (klo) {
#pragma unroll
            for (int q = 0; q < 4; ++q)
#pragma unroll
                for (int ff = 0; ff < 4; ++ff)
                    x[q * 4 + ff] = PW[row + f * 16 + q * 4 + ff];
        }
        LGKM();
        if (!klo) {
#pragma unroll
            for (int r = 0; r < 16; ++r) PW[row + r * 4 + f] = x[r];
        }
        LGKM();
        if (!klo) {
#pragma unroll
            for (int q = 0; q < 4; ++q)
#pragma unroll
                for (int ff = 0; ff < 4; ++ff)
                    x[q * 4 + ff] = PW[row + f * 16 + q * 4 + ff];
        }
    }

    // phase D: DFT4 over ff
#pragma unroll
    for (int q = 0; q < 4; ++q) dft4<false>(x[4*q], x[4*q+1], x[4*q+2], x[4*q+3]);
}

// ---------------- inverse: exact mirror; output x[a] = 16384 * time[a*1024+t]
__device__ __forceinline__ void fft_inv(float2* x, float2* SH, int t) {
    const int w  = t >> 6;
    const int d  = t & 63;
    const int kb = (t >> 2) & 15;
    const int f  = t & 3;
    float2* PW = SH + w * PW_STRIDE;
    float2 tmp[8];

    // phase D'
#pragma unroll
    for (int q = 0; q < 4; ++q) dft4<true>(x[4*q], x[4*q+1], x[4*q+2], x[4*q+3]);

    // ---- exchange D' (diagonal mirror of C) ----
    {
        const int row = (kb & 7) * 66;
        const bool klo = (kb < 8);
        LGKM();   // ensure fwd phase-C reads fully drained before overwrite
        if (klo) {
#pragma unroll
            for (int q = 0; q < 4; ++q)
#pragma unroll
                for (int ff = 0; ff < 4; ++ff)
                    PW[row + f * 16 + q * 4 + ff] = x[q * 4 + ff];
        }
        LGKM();
        if (klo) {
#pragma unroll
            for (int r = 0; r < 16; ++r) x[r] = PW[row + r * 4 + f];
        }
        LGKM();
        if (!klo) {
#pragma unroll
            for (int q = 0; q < 4; ++q)
#pragma unroll
                for (int ff = 0; ff < 4; ++ff)
                    PW[row + f * 16 + q * 4 + ff] = x[q * 4 + ff];
        }
        LGKM();
        if (!klo) {
#pragma unroll
            for (int r = 0; r < 16; ++r) x[r] = PW[row + r * 4 + f];
        }
    }

    // phase C'
    twiddle_apply(x, TWO_PI * (float)f * (1.0f / 64.0f));
    dft16<true, false>(x);

    // ---- exchange C'->B' (intra-wave): write row kb col e*4+f, read row r col d
    // row-split by writer kb; slot = (row&7)*66 + col
    {
        const int row = (kb & 7) * 66;
        const bool klo = (kb < 8);
        LGKM();
        if (klo) {
#pragma unroll
            for (int e = 0; e < 16; ++e) PW[row + e * 4 + f] = x[e];
        }
        LGKM();
#pragma unroll
        for (int r = 0; r < 8; ++r) {
            float2 v = PW[r * 66 + d];
            if (klo) x[r] = v; else tmp[r] = v;
        }
        LGKM();
        if (!klo) {
#pragma unroll
            for (int e = 0; e < 16; ++e) PW[row + e * 4 + f] = x[e];
        }
        LGKM();
#pragma unroll
        for (int r = 8; r < 16; ++r) x[r] = PW[(r - 8) * 66 + d];
        if (!klo) {
#pragma unroll
            for (int r = 0; r < 8; ++r) x[r] = tmp[r];
        }
    }

    // phase B'
    twiddle_apply(x, TWO_PI * (float)d * (1.0f / 1024.0f));
    dft16<true, false>(x);

    // ---- exchange B'->A': write p = w*1024 + c*64 + d, read p = r*1024 + t
    // row-split by writer wave through SH[0..8191]
    __syncthreads();   // all waves done with private-slice reads
    if (w < 8) {
#pragma unroll
        for (int c = 0; c < 16; ++c) SH[w * 1024 + c * 64 + d] = x[c];
    }
    __syncthreads();
#pragma unroll
    for (int r = 0; r < 8; ++r) {
        float2 v = SH[r * 1024 + t];
        if (w < 8) x[r] = v; else tmp[r] = v;
    }
    __syncthreads();
    if (w >= 8) {
#pragma unroll
        for (int c = 0; c < 16; ++c) SH[(w - 8) * 1024 + c * 64 + d] = x[c];
    }
    __syncthreads();
#pragma unroll
    for (int r = 8; r < 16; ++r) x[r] = SH[(r - 8) * 1024 + t];
    if (w >= 8) {
#pragma unroll
        for (int r = 0; r < 8; ++r) x[r] = tmp[r];
    }

    // phase A'
    twiddle_apply(x, TWO_PI * (float)t * (1.0f / 16384.0f));
    dft16<true, false>(x);
}

// ---------------- k0: W fp32 -> bf16 ----------------------------------------
__global__ void wconv(const float* __restrict__ W, ushort_t* __restrict__ Wb, int n)
{
    int i = blockIdx.x * 256 + threadIdx.x;
    if (i < n) Wb[i] = f2bf(W[i]);
}

// ---------------- k1: Kf[h][sigma] = FFT(k[h]) + D[h] -----------------------
__global__ __launch_bounds__(1024, 8) void kf_build(const float* __restrict__ k,
                                                    const float* __restrict__ D,
                                                    float2* __restrict__ Kf)
{
    __shared__ float2 SH[SH_SIZE];   // 71,680 B -> 2 blocks/CU
    int h = blockIdx.x, t = threadIdx.x;
    const float* kr = k + (size_t)h * 8192;
    float2 x[16];
#pragma unroll
    for (int a = 0; a < 8; ++a) x[a] = make_float2(kr[a * 1024 + t], 0.f);
#pragma unroll
    for (int a = 8; a < 16; ++a) x[a] = make_float2(0.f, 0.f);
    fft_fwd(x, SH, t);
    float dh = D[h];
    float2* o = Kf + (size_t)h * 16384;
#pragma unroll
    for (int r = 0; r < 16; ++r) {
        float2 z = x[r];
        z.x += dh;                       // FFT(D*delta) = D on every bin
        o[r * 1024 + t] = z;
    }
}

// ---------------- k2: conv + D-skip + GELU -> g bf16 ------------------------
__global__ __launch_bounds__(1024, 8) void conv_gelu(const float* __restrict__ u,
                                                     const float2* __restrict__ Kf,
                                                     ushort_t* __restrict__ g)
{
    __shared__ float2 SH[SH_SIZE];   // 71,680 B -> 2 blocks/CU
    int h    = blockIdx.x;         // 512
    int pair = blockIdx.y;         // 4
    int b0   = pair * 2;
    int t    = threadIdx.x;
    const float* u0 = u + ((size_t)(b0 * 512 + h)) * 8192;
    const float* u1 = u0 + (size_t)512 * 8192;
    float2 x[16];
#pragma unroll
    for (int a = 0; a < 8; ++a) x[a] = make_float2(u0[a * 1024 + t], u1[a * 1024 + t]);
#pragma unroll
    for (int a = 8; a < 16; ++a) x[a] = make_float2(0.f, 0.f);
    fft_fwd(x, SH, t);
    const float2* kf = Kf + (size_t)blockIdx.x * 16384;
#pragma unroll
    for (int r = 0; r < 16; ++r) x[r] = cmulf(x[r], kf[r * 1024 + t]);
    fft_inv(x, SH, t);
    const float sc = 1.0f / 16384.0f;
    ushort_t* g0 = g + ((size_t)(b0 * 512 + blockIdx.x)) * 8192;
    ushort_t* g1 = g0 + (size_t)512 * 8192;
#pragma unroll
    for (int a = 0; a < 8; ++a) {
        int n = a * 1024 + t;
        g0[n] = f2bf(gelu_exact(x[a].x * sc));   // batch b0
        g1[n] = f2bf(gelu_exact(x[a].y * sc));   // batch b0+1
    }
}

// ---------------- kT: g[b][h][l] -> gT[b][l][h] -----------------------------
__global__ __launch_bounds__(256) void transpose_g(const ushort_t* __restrict__ g,
                                                   ushort_t* __restrict__ gT)
{
    __shared__ ushort_t TL[64][68];   // [l][h], padded
    int lt = blockIdx.x;   // 128 l-tiles of 64
    int ht = blockIdx.y;   // 8 h-tiles of 64
    int b  = blockIdx.z;   // 8
    int t  = threadIdx.x;
    int l0 = lt * 64, h0 = ht * 64;
#pragma unroll
    for (int i = 0; i < 4; ++i) {
        int c   = t + (i << 8);        // 0..1023 ushort4-chunks
        int row = c >> 4;              // h-row 0..63
        int col = (c & 15) * 4;        // l-col
        const ushort_t* src = g + ((size_t)(b * 512 + h0 + row)) * 8192 + l0 + col;
        ushort4 v = *(const ushort4*)src;
        TL[col + 0][row] = v.x;
        TL[col + 1][row] = v.y;
        TL[col + 2][row] = v.z;
        TL[col + 3][row] = v.w;
    }
    __syncthreads();
#pragma unroll
    for (int i = 0; i < 4; ++i) {
        int c    = t + (i << 8);
        int lrow = c >> 4;
        int hcol = (c & 15) * 4;
        ushort4 v = *(const ushort4*)&TL[lrow][hcol];
        *(ushort4*)(gT + ((size_t)b * 8192 + l0 + lrow) * 512 + h0 + hcol) = v;
    }
}

// ---------------- k3: out[b,o,l] = sum_d Wb[o,d]*gT[b,l,d] + bias[o] --------
__global__ __launch_bounds__(256, 2) void gemm_out(const ushort_t* __restrict__ Wb,
                                                   const ushort_t* __restrict__ gT,
                                                   const float* __restrict__ bias,
                                                   float* __restrict__ out)
{
    __shared__ __align__(16) ushort_t As[128 * 32];  // [o][k]
    __shared__ __align__(16) ushort_t Bs[128 * 32];  // [l][k]
    int lt = blockIdx.x;   // 64 l-tiles
    int ot = blockIdx.y;   // 4 o-tiles
    int b  = blockIdx.z;   // 8
    int l0 = lt * 128, o0 = ot * 128;
    int t    = threadIdx.x;
    int wave = t >> 6, lid = t & 63;
    int wm = wave >> 1, wn = wave & 1;
    int q  = lid >> 4, mi = lid & 15;

    f32x4 acc[4][4];
#pragma unroll
    for (int i = 0; i < 4; ++i)
#pragma unroll
        for (int j = 0; j < 4; ++j)
            acc[i][j] = (f32x4){0.f, 0.f, 0.f, 0.f};

    const size_t gTb = (size_t)b * 8192 * 512;
    for (int it = 0; it < 16; ++it) {
        int k0 = it * 32;
        __syncthreads();
#pragma unroll
        for (int i = 0; i < 2; ++i) {
            int ch  = t + (i << 8);          // 0..511 16B-chunks
            int row = ch >> 2;
            int kc  = (ch & 3) << 3;
            uint4 va = *(const uint4*)(Wb + (size_t)(o0 + row) * 512 + k0 + kc);
            *(uint4*)&As[row * 32 + kc] = va;
            uint4 vb = *(const uint4*)(gT + gTb + (size_t)(l0 + row) * 512 + k0 + kc);
            *(uint4*)&Bs[row * 32 + kc] = vb;
        }
        __syncthreads();
        bf16x8 af[4], bfr[4];
#pragma unroll
        for (int ff = 0; ff < 4; ++ff) {
            af[ff]  = *(const bf16x8*)&As[(wm * 64 + ff * 16 + mi) * 32 + q * 8];
            bfr[ff] = *(const bf16x8*)&Bs[(wn * 64 + ff * 16 + mi) * 32 + q * 8];
        }
#pragma unroll
        for (int i = 0; i < 4; ++i)
#pragma unroll
            for (int j = 0; j < 4; ++j)
                acc[i][j] = __builtin_amdgcn_mfma_f32_16x16x32_bf16(af[i], bfr[j], acc[i][j], 0, 0, 0);
    }

#pragma unroll
    for (int i = 0; i < 4; ++i) {
        int o_base = o0 + wm * 64 + i * 16 + q * 4;
#pragma unroll
        for (int j = 0; j < 4; ++j) {
            int l = l0 + wn * 64 + j * 16 + mi;
#pragma unroll
            for (int r = 0; r < 4; ++r) {
                int o = o_base + r;
                out[((size_t)b * 512 + o) * 8192 + l] = acc[i][j][r] + bias[o];
            }
        }
    }
}

// ----------------------------------------------------------------------------
extern "C" void kernel_launch(void* const* d_in, const int* in_sizes, int n_in,
                              void* d_out, int out_size, void* d_ws, size_t ws_size,
                              hipStream_t stream)
{
    (void)in_sizes; (void)n_in; (void)out_size; (void)ws_size;
    const float* u    = (const float*)d_in[0];   // (8,512,8192)
    const float* k    = (const float*)d_in[1];   // (1,512,8192)
    const float* D    = (const float*)d_in[2];   // (1,512)
    const float* W    = (const float*)d_in[3];   // (512,512)
    const float* bias = (const float*)d_in[4];   // (512,)
    float* out = (float*)d_out;

    char* ws = (char*)d_ws;
    float2*   Kf = (float2*)ws;                          // 512*16384*8 = 64 MB
    ushort_t* gT = (ushort_t*)(ws + 67108864);           // 64 MB
    ushort_t* Wb = (ushort_t*)(ws + 134217728);          // 512 KB
    ushort_t* g  = (ushort_t*)d_out;                     // 64 MB staged in out buf

    wconv<<<1024, 256, 0, stream>>>(W, Wb, 512 * 512);
    kf_build<<<512, 1024, 0, stream>>>(k, D, Kf);
    conv_gelu<<<dim3(512, 4), 1024, 0, stream>>>(u, Kf, g);
    transpose_g<<<dim3(128, 8, 8), 256, 0, stream>>>(g, gT);
    gemm_out<<<dim3(64, 4, 8), 256, 0, stream>>>(Wb, gT, bias, out);
}

// Round 2
// 499.487 us; speedup vs baseline: 2.6541x; 2.6541x over previous
//
#include <hip/hip_runtime.h>

// ----------------------------------------------------------------------------
// S4 block: y = GELU( irfft(rfft(u,2L) * (rfft(k,2L) + D)) [:L] ) ; out = W@y + b
// B=8, C=1, H=512, L=8192, N=2L=16384
//
// FFT: four-step register-resident factorization 16384 = 16*16*16*4.
//   1024 threads, 16 complex points/thread in VGPRs. 16-point DFTs with
//   hard-coded twiddles. LDS restructured to 71,680 B (vs 139 KB) so TWO
//   blocks co-reside per CU (32 waves):
//     - exchange A (cross-wave transpose): 2 column-rounds through an
//       8192-float2 buffer (+tmp[8] staging for not-yet-dumped waves)
//     - exchanges B/C are intra-wave: per-wave private 560-float2 slices,
//       ordered by s_waitcnt lgkmcnt(0) only -- NO block barriers.
//   Inverse is the exact mirror. Scrambled bin order sigma is shared by
//   kf_build and conv_gelu, so the pointwise product is order-consistent.
//
// __launch_bounds__(1024, 1): do NOT force waves/EU. Round-1 lesson: forcing
//   (1024,8) made the allocator spill catastrophically (VGPR=32, +3 GB scratch
//   traffic, 15% VALUBusy). Natural allocation lands at the 64-VGPR tier
//   (x[16]+tmp[8] liveness is disjoint from dft16's working set), which is
//   exactly what 2 blocks/CU needs; LDS 71,680 B allows 2 blocks.
// ----------------------------------------------------------------------------

typedef unsigned short ushort_t;
typedef __bf16 bf16x8 __attribute__((ext_vector_type(8)));
typedef float  f32x4  __attribute__((ext_vector_type(4)));

#define TWO_PI 6.283185307179586f
#define LGKM() asm volatile("s_waitcnt lgkmcnt(0)" ::: "memory")

__device__ __forceinline__ float2 cmulf(float2 a, float2 b) {
    return make_float2(a.x * b.x - a.y * b.y, a.x * b.y + a.y * b.x);
}
__device__ __forceinline__ float2 caddf(float2 a, float2 b) { return make_float2(a.x + b.x, a.y + b.y); }
__device__ __forceinline__ float2 csubf(float2 a, float2 b) { return make_float2(a.x - b.x, a.y - b.y); }

__device__ __forceinline__ ushort_t f2bf(float f) {
    unsigned int u = __float_as_uint(f);
    u = (u + 0x7fffu + ((u >> 16) & 1u)) >> 16;
    return (ushort_t)u;
}

__device__ __forceinline__ float gelu_exact(float x) {
    return 0.5f * x * (1.0f + erff(x * 0.70710678118654752f));
}

// ---------------- 4-point DFT, natural in/out (INV = conjugate kernel) ------
template<bool INV>
__device__ __forceinline__ void dft4(float2& x0, float2& x1, float2& x2, float2& x3) {
    float2 t0 = caddf(x0, x2), t1 = csubf(x0, x2);
    float2 t2 = caddf(x1, x3), t3 = csubf(x1, x3);
    x0 = caddf(t0, t2);
    x2 = csubf(t0, t2);
    if (!INV) {
        x1 = make_float2(t1.x + t3.y, t1.y - t3.x);   // t1 - i*t3
        x3 = make_float2(t1.x - t3.y, t1.y + t3.x);   // t1 + i*t3
    } else {
        x1 = make_float2(t1.x - t3.y, t1.y + t3.x);
        x3 = make_float2(t1.x + t3.y, t1.y - t3.x);
    }
}

// multiply by twiddle (wr, wi); INV conjugates the twiddle
template<bool INV>
__device__ __forceinline__ float2 cmulc(float2 a, float wr, float wi) {
    float i2 = INV ? -wi : wi;
    return make_float2(a.x * wr - a.y * i2, a.x * i2 + a.y * wr);
}

#define C1_ 0.9238795325112867f
#define S1_ 0.3826834323650898f
#define R2_ 0.7071067811865476f

// ---------------- 16-point DFT, natural in/out ------------------------------
// four-step 16 = 4x4: n = 4a+b, k = c+4e.
// HZ: inputs r[8..15] are known-zero (skip half the inner butterflies).
template<bool INV, bool HZ>
__device__ __forceinline__ void dft16(float2* r) {
#pragma unroll
    for (int b = 0; b < 4; ++b) {
        if (HZ) {
            float2 u = r[b], v = r[4 + b];
            r[b]     = caddf(u, v);
            r[8 + b] = csubf(u, v);
            if (!INV) { r[4 + b]  = make_float2(u.x + v.y, u.y - v.x);
                        r[12 + b] = make_float2(u.x - v.y, u.y + v.x); }
            else      { r[4 + b]  = make_float2(u.x - v.y, u.y + v.x);
                        r[12 + b] = make_float2(u.x + v.y, u.y - v.x); }
        } else {
            dft4<INV>(r[b], r[4 + b], r[8 + b], r[12 + b]);
        }
    }
    // twiddle r[4c+b] *= w16^{bc}
    r[5]  = cmulc<INV>(r[5],  C1_, -S1_);   // w^1
    r[6]  = cmulc<INV>(r[6],  R2_, -R2_);   // w^2
    r[7]  = cmulc<INV>(r[7],  S1_, -C1_);   // w^3
    r[9]  = cmulc<INV>(r[9],  R2_, -R2_);   // w^2
    r[10] = cmulc<INV>(r[10], 0.f, -1.f);   // w^4
    r[11] = cmulc<INV>(r[11], -R2_, -R2_);  // w^6
    r[13] = cmulc<INV>(r[13], S1_, -C1_);   // w^3
    r[14] = cmulc<INV>(r[14], -R2_, -R2_);  // w^6
    r[15] = cmulc<INV>(r[15], -C1_,  S1_);  // w^9
    float2 o[16];
#pragma unroll
    for (int c = 0; c < 4; ++c) {
        float2 a0 = r[4*c], a1 = r[4*c+1], a2 = r[4*c+2], a3 = r[4*c+3];
        dft4<INV>(a0, a1, a2, a3);
        o[c] = a0; o[c + 4] = a1; o[c + 8] = a2; o[c + 12] = a3;
    }
#pragma unroll
    for (int i = 0; i < 16; ++i) r[i] = o[i];
}

// apply w^k, w = e^{i*theta}, to x[1..15] (x[0] *= w^0)
__device__ __forceinline__ void twiddle_apply(float2* x, float theta) {
    float s, c;
    __sincosf(theta, &s, &c);
    float2 w = make_float2(c, s), wk = w;
#pragma unroll
    for (int k = 1; k < 16; ++k) { x[k] = cmulf(x[k], wk); wk = cmulf(wk, w); }
}

// ----------------------------------------------------------------------------
// Shared scratch: 8960 float2 = 71,680 B  -> 2 blocks/CU.
//   [0, 8192)        : exchange-A / exchange-BA' half-signal buffer
//   SH + w*560       : wave-private slice for exchanges B, C (and mirrors)
// ----------------------------------------------------------------------------
#define SH_SIZE 8960
#define PW_STRIDE 560

// ---------------- forward: regs(natural a-chunks) -> regs(sigma bins) -------
// thread t holds x[a] = in[a*1024 + t] (a=8..15 zero). Output: 16 sigma-bins.
__device__ __forceinline__ void fft_fwd(float2* x, float2* SH, int t) {
    const int w  = t >> 6;          // wave / k1
    const int d  = t & 63;
    const int kb = (t >> 2) & 15;
    const int f  = t & 3;
    float2* PW = SH + w * PW_STRIDE;
    float2 tmp[8];
    const bool tlo = (t < 512);

    // phase A: DFT16 over a (half-zero) + twiddle w_N^t
    dft16<false, true>(x);
    twiddle_apply(x, -TWO_PI * (float)t * (1.0f / 16384.0f));

    // ---- exchange A: logical pos p = r*1024 + t' ; read p = w*1024 + c*64 + d
    // col-split rounds through SH[0..8191], slot = r*512 + (t' & 511)
    if (tlo) {
#pragma unroll
        for (int r = 0; r < 16; ++r) SH[r * 512 + t] = x[r];
    }
    __syncthreads();
#pragma unroll
    for (int c = 0; c < 8; ++c) {
        float2 v = SH[w * 512 + c * 64 + d];
        if (tlo) x[c] = v; else tmp[c] = v;
    }
    __syncthreads();
    if (!tlo) {
#pragma unroll
        for (int r = 0; r < 16; ++r) SH[r * 512 + (t - 512)] = x[r];
    }
    __syncthreads();
#pragma unroll
    for (int c = 8; c < 16; ++c) x[c] = SH[w * 512 + (c - 8) * 64 + d];
    if (!tlo) {
#pragma unroll
        for (int c = 0; c < 8; ++c) x[c] = tmp[c];
    }

    // phase B: DFT16 over c + twiddle w_1024^d
    dft16<false, false>(x);
    twiddle_apply(x, -TWO_PI * (float)d * (1.0f / 1024.0f));
    __syncthreads();   // all waves done reading SH[0..8191]; private slices now safe

    // ---- exchange B (intra-wave): write row r col d, read row kb col e*4+f
    // col-split by d; per-wave slot = r*33 + (d & 31); NO barriers.
    {
        const bool dlo = (d < 32);
        const int dc = d & 31;
        if (dlo) {
#pragma unroll
            for (int r = 0; r < 16; ++r) PW[r * 33 + dc] = x[r];
        }
        LGKM();
#pragma unroll
        for (int e = 0; e < 8; ++e) {
            float2 v = PW[kb * 33 + e * 4 + f];
            if (dlo) x[e] = v; else tmp[e] = v;
        }
        LGKM();
        if (!dlo) {
#pragma unroll
            for (int r = 0; r < 16; ++r) PW[r * 33 + dc] = x[r];
        }
        LGKM();
#pragma unroll
        for (int e = 8; e < 16; ++e) x[e] = PW[kb * 33 + (e - 8) * 4 + f];
        if (!dlo) {
#pragma unroll
            for (int e = 0; e < 8; ++e) x[e] = tmp[e];
        }
    }

    // phase C: DFT16 over e + twiddle w_64^f
    dft16<false, false>(x);
    twiddle_apply(x, -TWO_PI * (float)f * (1.0f / 64.0f));

    // ---- exchange C (intra-wave, kb-diagonal): half-wave sequential rounds
    // slot = (kb&7)*66 + col; write col = r*4+f, read col = f*16 + q*4 + ff
    {
        const int row = (kb & 7) * 66;
        const bool klo = (kb < 8);
        if (klo) {
#pragma unroll
            for (int r = 0; r < 16; ++r) PW[row + r * 4 + f] = x[r];
        }
        LGKM();
        if (klo) {
#pragma unroll
            for (int q = 0; q < 4; ++q)
#pragma unroll
                for (int ff = 0; ff < 4; ++ff)
                    x[q * 4 + ff] = PW[row + f * 16 + q * 4 + ff];
        }
        LGKM();
        if (!klo) {
#pragma unroll
            for (int r = 0; r < 16; ++r) PW[row + r * 4 + f] = x[r];
        }
        LGKM();
        if (!klo) {
#pragma unroll
            for (int q = 0; q < 4; ++q)
#pragma unroll
                for (int ff = 0; ff < 4; ++ff)
                    x[q * 4 + ff] = PW[row + f * 16 + q * 4 + ff];
        }
    }

    // phase D: DFT4 over ff
#pragma unroll
    for (int q = 0; q < 4; ++q) dft4<false>(x[4*q], x[4*q+1], x[4*q+2], x[4*q+3]);
}

// ---------------- inverse: exact mirror; output x[a] = 16384 * time[a*1024+t]
__device__ __forceinline__ void fft_inv(float2* x, float2* SH, int t) {
    const int w  = t >> 6;
    const int d  = t & 63;
    const int kb = (t >> 2) & 15;
    const int f  = t & 3;
    float2* PW = SH + w * PW_STRIDE;
    float2 tmp[8];

    // phase D'
#pragma unroll
    for (int q = 0; q < 4; ++q) dft4<true>(x[4*q], x[4*q+1], x[4*q+2], x[4*q+3]);

    // ---- exchange D' (diagonal mirror of C) ----
    {
        const int row = (kb & 7) * 66;
        const bool klo = (kb < 8);
        LGKM();   // ensure fwd phase-C reads fully drained before overwrite
        if (klo) {
#pragma unroll
            for (int q = 0; q < 4; ++q)
#pragma unroll
                for (int ff = 0; ff < 4; ++ff)
                    PW[row + f * 16 + q * 4 + ff] = x[q * 4 + ff];
        }
        LGKM();
        if (klo) {
#pragma unroll
            for (int r = 0; r < 16; ++r) x[r] = PW[row + r * 4 + f];
        }
        LGKM();
        if (!klo) {
#pragma unroll
            for (int q = 0; q < 4; ++q)
#pragma unroll
                for (int ff = 0; ff < 4; ++ff)
                    PW[row + f * 16 + q * 4 + ff] = x[q * 4 + ff];
        }
        LGKM();
        if (!klo) {
#pragma unroll
            for (int r = 0; r < 16; ++r) x[r] = PW[row + r * 4 + f];
        }
    }

    // phase C'
    twiddle_apply(x, TWO_PI * (float)f * (1.0f / 64.0f));
    dft16<true, false>(x);

    // ---- exchange C'->B' (intra-wave): write row kb col e*4+f, read row r col d
    // row-split by writer kb; slot = (row&7)*66 + col
    {
        const int row = (kb & 7) * 66;
        const bool klo = (kb < 8);
        LGKM();
        if (klo) {
#pragma unroll
            for (int e = 0; e < 16; ++e) PW[row + e * 4 + f] = x[e];
        }
        LGKM();
#pragma unroll
        for (int r = 0; r < 8; ++r) {
            float2 v = PW[r * 66 + d];
            if (klo) x[r] = v; else tmp[r] = v;
        }
        LGKM();
        if (!klo) {
#pragma unroll
            for (int e = 0; e < 16; ++e) PW[row + e * 4 + f] = x[e];
        }
        LGKM();
#pragma unroll
        for (int r = 8; r < 16; ++r) x[r] = PW[(r - 8) * 66 + d];
        if (!klo) {
#pragma unroll
            for (int r = 0; r < 8; ++r) x[r] = tmp[r];
        }
    }

    // phase B'
    twiddle_apply(x, TWO_PI * (float)d * (1.0f / 1024.0f));
    dft16<true, false>(x);

    // ---- exchange B'->A': write p = w*1024 + c*64 + d, read p = r*1024 + t
    // row-split by writer wave through SH[0..8191]
    __syncthreads();   // all waves done with private-slice reads
    if (w < 8) {
#pragma unroll
        for (int c = 0; c < 16; ++c) SH[w * 1024 + c * 64 + d] = x[c];
    }
    __syncthreads();
#pragma unroll
    for (int r = 0; r < 8; ++r) {
        float2 v = SH[r * 1024 + t];
        if (w < 8) x[r] = v; else tmp[r] = v;
    }
    __syncthreads();
    if (w >= 8) {
#pragma unroll
        for (int c = 0; c < 16; ++c) SH[(w - 8) * 1024 + c * 64 + d] = x[c];
    }
    __syncthreads();
#pragma unroll
    for (int r = 8; r < 16; ++r) x[r] = SH[(r - 8) * 1024 + t];
    if (w >= 8) {
#pragma unroll
        for (int r = 0; r < 8; ++r) x[r] = tmp[r];
    }

    // phase A'
    twiddle_apply(x, TWO_PI * (float)t * (1.0f / 16384.0f));
    dft16<true, false>(x);
}

// ---------------- k0: W fp32 -> bf16 ----------------------------------------
__global__ void wconv(const float* __restrict__ W, ushort_t* __restrict__ Wb, int n)
{
    int i = blockIdx.x * 256 + threadIdx.x;
    if (i < n) Wb[i] = f2bf(W[i]);
}

// ---------------- k1: Kf[h][sigma] = FFT(k[h]) + D[h] -----------------------
__global__ __launch_bounds__(1024, 1) void kf_build(const float* __restrict__ k,
                                                    const float* __restrict__ D,
                                                    float2* __restrict__ Kf)
{
    __shared__ float2 SH[SH_SIZE];   // 71,680 B -> 2 blocks/CU (if VGPR <= 64)
    int h = blockIdx.x, t = threadIdx.x;
    const float* kr = k + (size_t)h * 8192;
    float2 x[16];
#pragma unroll
    for (int a = 0; a < 8; ++a) x[a] = make_float2(kr[a * 1024 + t], 0.f);
#pragma unroll
    for (int a = 8; a < 16; ++a) x[a] = make_float2(0.f, 0.f);
    fft_fwd(x, SH, t);
    float dh = D[h];
    float2* o = Kf + (size_t)h * 16384;
#pragma unroll
    for (int r = 0; r < 16; ++r) {
        float2 z = x[r];
        z.x += dh;                       // FFT(D*delta) = D on every bin
        o[r * 1024 + t] = z;
    }
}

// ---------------- k2: conv + D-skip + GELU -> g bf16 ------------------------
__global__ __launch_bounds__(1024, 1) void conv_gelu(const float* __restrict__ u,
                                                     const float2* __restrict__ Kf,
                                                     ushort_t* __restrict__ g)
{
    __shared__ float2 SH[SH_SIZE];   // 71,680 B -> 2 blocks/CU (if VGPR <= 64)
    int h    = blockIdx.x;         // 512
    int pair = blockIdx.y;         // 4
    int b0   = pair * 2;
    int t    = threadIdx.x;
    const float* u0 = u + ((size_t)(b0 * 512 + h)) * 8192;
    const float* u1 = u0 + (size_t)512 * 8192;
    float2 x[16];
#pragma unroll
    for (int a = 0; a < 8; ++a) x[a] = make_float2(u0[a * 1024 + t], u1[a * 1024 + t]);
#pragma unroll
    for (int a = 8; a < 16; ++a) x[a] = make_float2(0.f, 0.f);
    fft_fwd(x, SH, t);
    const float2* kf = Kf + (size_t)blockIdx.x * 16384;
#pragma unroll
    for (int r = 0; r < 16; ++r) x[r] = cmulf(x[r], kf[r * 1024 + t]);
    fft_inv(x, SH, t);
    const float sc = 1.0f / 16384.0f;
    ushort_t* g0 = g + ((size_t)(b0 * 512 + blockIdx.x)) * 8192;
    ushort_t* g1 = g0 + (size_t)512 * 8192;
#pragma unroll
    for (int a = 0; a < 8; ++a) {
        int n = a * 1024 + t;
        g0[n] = f2bf(gelu_exact(x[a].x * sc));   // batch b0
        g1[n] = f2bf(gelu_exact(x[a].y * sc));   // batch b0+1
    }
}

// ---------------- kT: g[b][h][l] -> gT[b][l][h] -----------------------------
__global__ __launch_bounds__(256) void transpose_g(const ushort_t* __restrict__ g,
                                                   ushort_t* __restrict__ gT)
{
    __shared__ ushort_t TL[64][68];   // [l][h], padded
    int lt = blockIdx.x;   // 128 l-tiles of 64
    int ht = blockIdx.y;   // 8 h-tiles of 64
    int b  = blockIdx.z;   // 8
    int t  = threadIdx.x;
    int l0 = lt * 64, h0 = ht * 64;
#pragma unroll
    for (int i = 0; i < 4; ++i) {
        int c   = t + (i << 8);        // 0..1023 ushort4-chunks
        int row = c >> 4;              // h-row 0..63
        int col = (c & 15) * 4;        // l-col
        const ushort_t* src = g + ((size_t)(b * 512 + h0 + row)) * 8192 + l0 + col;
        ushort4 v = *(const ushort4*)src;
        TL[col + 0][row] = v.x;
        TL[col + 1][row] = v.y;
        TL[col + 2][row] = v.z;
        TL[col + 3][row] = v.w;
    }
    __syncthreads();
#pragma unroll
    for (int i = 0; i < 4; ++i) {
        int c    = t + (i << 8);
        int lrow = c >> 4;
        int hcol = (c & 15) * 4;
        ushort4 v = *(const ushort4*)&TL[lrow][hcol];
        *(ushort4*)(gT + ((size_t)b * 8192 + l0 + lrow) * 512 + h0 + hcol) = v;
    }
}

// ---------------- k3: out[b,o,l] = sum_d Wb[o,d]*gT[b,l,d] + bias[o] --------
__global__ __launch_bounds__(256, 2) void gemm_out(const ushort_t* __restrict__ Wb,
                                                   const ushort_t* __restrict__ gT,
                                                   const float* __restrict__ bias,
                                                   float* __restrict__ out)
{
    __shared__ __align__(16) ushort_t As[128 * 32];  // [o][k]
    __shared__ __align__(16) ushort_t Bs[128 * 32];  // [l][k]
    int lt = blockIdx.x;   // 64 l-tiles
    int ot = blockIdx.y;   // 4 o-tiles
    int b  = blockIdx.z;   // 8
    int l0 = lt * 128, o0 = ot * 128;
    int t    = threadIdx.x;
    int wave = t >> 6, lid = t & 63;
    int wm = wave >> 1, wn = wave & 1;
    int q  = lid >> 4, mi = lid & 15;

    f32x4 acc[4][4];
#pragma unroll
    for (int i = 0; i < 4; ++i)
#pragma unroll
        for (int j = 0; j < 4; ++j)
            acc[i][j] = (f32x4){0.f, 0.f, 0.f, 0.f};

    const size_t gTb = (size_t)b * 8192 * 512;
    for (int it = 0; it < 16; ++it) {
        int k0 = it * 32;
        __syncthreads();
#pragma unroll
        for (int i = 0; i < 2; ++i) {
            int ch  = t + (i << 8);          // 0..511 16B-chunks
            int row = ch >> 2;
            int kc  = (ch & 3) << 3;
            uint4 va = *(const uint4*)(Wb + (size_t)(o0 + row) * 512 + k0 + kc);
            *(uint4*)&As[row * 32 + kc] = va;
            uint4 vb = *(const uint4*)(gT + gTb + (size_t)(l0 + row) * 512 + k0 + kc);
            *(uint4*)&Bs[row * 32 + kc] = vb;
        }
        __syncthreads();
        bf16x8 af[4], bfr[4];
#pragma unroll
        for (int ff = 0; ff < 4; ++ff) {
            af[ff]  = *(const bf16x8*)&As[(wm * 64 + ff * 16 + mi) * 32 + q * 8];
            bfr[ff] = *(const bf16x8*)&Bs[(wn * 64 + ff * 16 + mi) * 32 + q * 8];
        }
#pragma unroll
        for (int i = 0; i < 4; ++i)
#pragma unroll
            for (int j = 0; j < 4; ++j)
                acc[i][j] = __builtin_amdgcn_mfma_f32_16x16x32_bf16(af[i], bfr[j], acc[i][j], 0, 0, 0);
    }

#pragma unroll
    for (int i = 0; i < 4; ++i) {
        int o_base = o0 + wm * 64 + i * 16 + q * 4;
#pragma unroll
        for (int j = 0; j < 4; ++j) {
            int l = l0 + wn * 64 + j * 16 + mi;
#pragma unroll
            for (int r = 0; r < 4; ++r) {
                int o = o_base + r;
                out[((size_t)b * 512 + o) * 8192 + l] = acc[i][j][r] + bias[o];
            }
        }
    }
}

// ----------------------------------------------------------------------------
extern "C" void kernel_launch(void* const* d_in, const int* in_sizes, int n_in,
                              void* d_out, int out_size, void* d_ws, size_t ws_size,
                              hipStream_t stream)
{
    (void)in_sizes; (void)n_in; (void)out_size; (void)ws_size;
    const float* u    = (const float*)d_in[0];   // (8,512,8192)
    const float* k    = (const float*)d_in[1];   // (1,512,8192)
    const float* D    = (const float*)d_in[2];   // (1,512)
    const float* W    = (const float*)d_in[3];   // (512,512)
    const float* bias = (const float*)d_in[4];   // (512,)
    float* out = (float*)d_out;

    char* ws = (char*)d_ws;
    float2*   Kf = (float2*)ws;                          // 512*16384*8 = 64 MB
    ushort_t* gT = (ushort_t*)(ws + 67108864);           // 64 MB
    ushort_t* Wb = (ushort_t*)(ws + 134217728);          // 512 KB
    ushort_t* g  = (ushort_t*)d_out;                     // 64 MB staged in out buf

    wconv<<<1024, 256, 0, stream>>>(W, Wb, 512 * 512);
    kf_build<<<512, 1024, 0, stream>>>(k, D, Kf);
    conv_gelu<<<dim3(512, 4), 1024, 0, stream>>>(u, Kf, g);
    transpose_g<<<dim3(128, 8, 8), 256, 0, stream>>>(g, gT);
    gemm_out<<<dim3(64, 4, 8), 256, 0, stream>>>(Wb, gT, bias, out);
}

// Round 4
// 478.554 us; speedup vs baseline: 2.7702x; 1.0437x over previous
//
#include <hip/hip_runtime.h>

// ----------------------------------------------------------------------------
// S4 block: y = GELU( irfft(rfft(u,2L) * (rfft(k,2L) + D)) [:L] ) ; out = W@y + b
// B=8, C=1, H=512, L=8192, N=2L=16384
//
// FFT: four-step register-resident factorization 16384 = 16*16*16*4.
//   1024 threads, 16 complex points/thread in VGPRs. 16-point DFTs with
//   hard-coded twiddles. LDS = 73,728 B:
//     - exchange A (cross-wave transpose): 2 column-rounds through an
//       8192-float2 buffer (+tmp[8] staging for not-yet-dumped waves)
//     - exchanges B/C intra-wave: per-wave private 576-float2 slices,
//       ordered by s_waitcnt lgkmcnt(0) only -- NO block barriers.
//   Inverse is the exact mirror. Scrambled bin order sigma is shared by
//   kf_build and conv_gelu, so the pointwise product is order-consistent.
//
// Bank-conflict layout (R3): all per-wave slice accesses are bank-bijective
//   per 16-lane phase (float2 pair-bank = slot mod 16):
//   - exchange B stride 33 -> 36 (36 == 4 mod 16: read (4kb+f) mod 16 bijective)
//   - exchange C/D'/C'B' row stride 66 -> 68 + column swizzle
//     CHI(p) = (p&0x3C) | ((p + (p>>4)) & 3)  -- bijection on [0,64) that puts
//     read-f (bits 0-1) AND write-f' (bits 4-5) into the mod-4 bank residue.
//     Applied on both write and read -> cancels semantically.
//   R2 measured 19.9M conflict-cycles (~13% of kernel); this removes them.
//
// __launch_bounds__(1024, 1): do NOT force waves/EU. R1 lesson: forcing (1024,8)
//   clamps to 32 VGPR -> catastrophic scratch spills. R2 lesson: VGPR=64 runs at
//   4 waves/SIMD (16 waves/CU) -- register file grants only 256 arch VGPR/EU
//   here (AGPR-shadow), so 2-block residency is unreachable without re-spilling.
//   Accept 1 block/CU; optimize the intra-block critical path instead.
//
// (R3 bench was an infra failure -- container acquisition -- resubmitting
//  the identical kernel for measurement.)
// ----------------------------------------------------------------------------

typedef unsigned short ushort_t;
typedef __bf16 bf16x8 __attribute__((ext_vector_type(8)));
typedef float  f32x4  __attribute__((ext_vector_type(4)));

#define TWO_PI 6.283185307179586f
#define LGKM() asm volatile("s_waitcnt lgkmcnt(0)" ::: "memory")
#define CHI(p) ((((p) & 0x3C)) | (((p) + ((p) >> 4)) & 3))

__device__ __forceinline__ float2 cmulf(float2 a, float2 b) {
    return make_float2(a.x * b.x - a.y * b.y, a.x * b.y + a.y * b.x);
}
__device__ __forceinline__ float2 caddf(float2 a, float2 b) { return make_float2(a.x + b.x, a.y + b.y); }
__device__ __forceinline__ float2 csubf(float2 a, float2 b) { return make_float2(a.x - b.x, a.y - b.y); }

__device__ __forceinline__ ushort_t f2bf(float f) {
    unsigned int u = __float_as_uint(f);
    u = (u + 0x7fffu + ((u >> 16) & 1u)) >> 16;
    return (ushort_t)u;
}

__device__ __forceinline__ float gelu_exact(float x) {
    return 0.5f * x * (1.0f + erff(x * 0.70710678118654752f));
}

// ---------------- 4-point DFT, natural in/out (INV = conjugate kernel) ------
template<bool INV>
__device__ __forceinline__ void dft4(float2& x0, float2& x1, float2& x2, float2& x3) {
    float2 t0 = caddf(x0, x2), t1 = csubf(x0, x2);
    float2 t2 = caddf(x1, x3), t3 = csubf(x1, x3);
    x0 = caddf(t0, t2);
    x2 = csubf(t0, t2);
    if (!INV) {
        x1 = make_float2(t1.x + t3.y, t1.y - t3.x);   // t1 - i*t3
        x3 = make_float2(t1.x - t3.y, t1.y + t3.x);   // t1 + i*t3
    } else {
        x1 = make_float2(t1.x - t3.y, t1.y + t3.x);
        x3 = make_float2(t1.x + t3.y, t1.y - t3.x);
    }
}

// multiply by twiddle (wr, wi); INV conjugates the twiddle
template<bool INV>
__device__ __forceinline__ float2 cmulc(float2 a, float wr, float wi) {
    float i2 = INV ? -wi : wi;
    return make_float2(a.x * wr - a.y * i2, a.x * i2 + a.y * wr);
}

#define C1_ 0.9238795325112867f
#define S1_ 0.3826834323650898f
#define R2_ 0.7071067811865476f

// ---------------- 16-point DFT, natural in/out ------------------------------
// four-step 16 = 4x4: n = 4a+b, k = c+4e.
// HZ: inputs r[8..15] are known-zero (skip half the inner butterflies).
template<bool INV, bool HZ>
__device__ __forceinline__ void dft16(float2* r) {
#pragma unroll
    for (int b = 0; b < 4; ++b) {
        if (HZ) {
            float2 u = r[b], v = r[4 + b];
            r[b]     = caddf(u, v);
            r[8 + b] = csubf(u, v);
            if (!INV) { r[4 + b]  = make_float2(u.x + v.y, u.y - v.x);
                        r[12 + b] = make_float2(u.x - v.y, u.y + v.x); }
            else      { r[4 + b]  = make_float2(u.x - v.y, u.y + v.x);
                        r[12 + b] = make_float2(u.x + v.y, u.y - v.x); }
        } else {
            dft4<INV>(r[b], r[4 + b], r[8 + b], r[12 + b]);
        }
    }
    // twiddle r[4c+b] *= w16^{bc}
    r[5]  = cmulc<INV>(r[5],  C1_, -S1_);   // w^1
    r[6]  = cmulc<INV>(r[6],  R2_, -R2_);   // w^2
    r[7]  = cmulc<INV>(r[7],  S1_, -C1_);   // w^3
    r[9]  = cmulc<INV>(r[9],  R2_, -R2_);   // w^2
    r[10] = cmulc<INV>(r[10], 0.f, -1.f);   // w^4
    r[11] = cmulc<INV>(r[11], -R2_, -R2_);  // w^6
    r[13] = cmulc<INV>(r[13], S1_, -C1_);   // w^3
    r[14] = cmulc<INV>(r[14], -R2_, -R2_);  // w^6
    r[15] = cmulc<INV>(r[15], -C1_,  S1_);  // w^9
    float2 o[16];
#pragma unroll
    for (int c = 0; c < 4; ++c) {
        float2 a0 = r[4*c], a1 = r[4*c+1], a2 = r[4*c+2], a3 = r[4*c+3];
        dft4<INV>(a0, a1, a2, a3);
        o[c] = a0; o[c + 4] = a1; o[c + 8] = a2; o[c + 12] = a3;
    }
#pragma unroll
    for (int i = 0; i < 16; ++i) r[i] = o[i];
}

// apply w^k, w = e^{i*theta}, to x[1..15] (x[0] *= w^0)
__device__ __forceinline__ void twiddle_apply(float2* x, float theta) {
    float s, c;
    __sincosf(theta, &s, &c);
    float2 w = make_float2(c, s), wk = w;
#pragma unroll
    for (int k = 1; k < 16; ++k) { x[k] = cmulf(x[k], wk); wk = cmulf(wk, w); }
}

// ----------------------------------------------------------------------------
// Shared scratch: 9216 float2 = 73,728 B.
//   [0, 8192)        : exchange-A / exchange-B'A' half-signal buffer
//   SH + w*576       : wave-private slice for exchanges B, C (and mirrors)
// ----------------------------------------------------------------------------
#define SH_SIZE 9216
#define PW_STRIDE 576

// ---------------- forward: regs(natural a-chunks) -> regs(sigma bins) -------
// thread t holds x[a] = in[a*1024 + t] (a=8..15 zero). Output: 16 sigma-bins.
__device__ __forceinline__ void fft_fwd(float2* x, float2* SH, int t) {
    const int w  = t >> 6;          // wave / k1
    const int d  = t & 63;
    const int kb = (t >> 2) & 15;
    const int f  = t & 3;
    float2* PW = SH + w * PW_STRIDE;
    float2 tmp[8];
    const bool tlo = (t < 512);

    // phase A: DFT16 over a (half-zero) + twiddle w_N^t
    dft16<false, true>(x);
    twiddle_apply(x, -TWO_PI * (float)t * (1.0f / 16384.0f));

    // ---- exchange A: logical pos p = r*1024 + t' ; read p = w*1024 + c*64 + d
    // col-split rounds through SH[0..8191], slot = r*512 + (t' & 511)
    if (tlo) {
#pragma unroll
        for (int r = 0; r < 16; ++r) SH[r * 512 + t] = x[r];
    }
    __syncthreads();
#pragma unroll
    for (int c = 0; c < 8; ++c) {
        float2 v = SH[w * 512 + c * 64 + d];
        if (tlo) x[c] = v; else tmp[c] = v;
    }
    __syncthreads();
    if (!tlo) {
#pragma unroll
        for (int r = 0; r < 16; ++r) SH[r * 512 + (t - 512)] = x[r];
    }
    __syncthreads();
#pragma unroll
    for (int c = 8; c < 16; ++c) x[c] = SH[w * 512 + (c - 8) * 64 + d];
    if (!tlo) {
#pragma unroll
        for (int c = 0; c < 8; ++c) x[c] = tmp[c];
    }

    // phase B: DFT16 over c + twiddle w_1024^d
    dft16<false, false>(x);
    twiddle_apply(x, -TWO_PI * (float)d * (1.0f / 1024.0f));
    __syncthreads();   // all waves done reading SH[0..8191]; private slices now safe

    // ---- exchange B (intra-wave): write row r col d, read row kb col e*4+f
    // col-split by d; per-wave slot = r*36 + (d & 31); NO barriers.
    // stride 36 == 4 (mod 16): read bank-pair (4kb+f) mod 16 bijective/group.
    {
        const bool dlo = (d < 32);
        const int dc = d & 31;
        if (dlo) {
#pragma unroll
            for (int r = 0; r < 16; ++r) PW[r * 36 + dc] = x[r];
        }
        LGKM();
#pragma unroll
        for (int e = 0; e < 8; ++e) {
            float2 v = PW[kb * 36 + e * 4 + f];
            if (dlo) x[e] = v; else tmp[e] = v;
        }
        LGKM();
        if (!dlo) {
#pragma unroll
            for (int r = 0; r < 16; ++r) PW[r * 36 + dc] = x[r];
        }
        LGKM();
#pragma unroll
        for (int e = 8; e < 16; ++e) x[e] = PW[kb * 36 + (e - 8) * 4 + f];
        if (!dlo) {
#pragma unroll
            for (int e = 0; e < 8; ++e) x[e] = tmp[e];
        }
    }

    // phase C: DFT16 over e + twiddle w_64^f
    dft16<false, false>(x);
    twiddle_apply(x, -TWO_PI * (float)f * (1.0f / 64.0f));

    // ---- exchange C (intra-wave, kb-diagonal): half-wave sequential rounds
    // slot = (kb&7)*68 + CHI(col); write col = r*4+f, read col = f*16 + q*4 + ff
    {
        const int row = (kb & 7) * 68;
        const bool klo = (kb < 8);
        if (klo) {
#pragma unroll
            for (int r = 0; r < 16; ++r) PW[row + CHI(r * 4 + f)] = x[r];
        }
        LGKM();
        if (klo) {
#pragma unroll
            for (int q = 0; q < 4; ++q)
#pragma unroll
                for (int ff = 0; ff < 4; ++ff)
                    x[q * 4 + ff] = PW[row + CHI(f * 16 + q * 4 + ff)];
        }
        LGKM();
        if (!klo) {
#pragma unroll
            for (int r = 0; r < 16; ++r) PW[row + CHI(r * 4 + f)] = x[r];
        }
        LGKM();
        if (!klo) {
#pragma unroll
            for (int q = 0; q < 4; ++q)
#pragma unroll
                for (int ff = 0; ff < 4; ++ff)
                    x[q * 4 + ff] = PW[row + CHI(f * 16 + q * 4 + ff)];
        }
    }

    // phase D: DFT4 over ff
#pragma unroll
    for (int q = 0; q < 4; ++q) dft4<false>(x[4*q], x[4*q+1], x[4*q+2], x[4*q+3]);
}

// ---------------- inverse: exact mirror; output x[a] = 16384 * time[a*1024+t]
__device__ __forceinline__ void fft_inv(float2* x, float2* SH, int t) {
    const int w  = t >> 6;
    const int d  = t & 63;
    const int kb = (t >> 2) & 15;
    const int f  = t & 3;
    float2* PW = SH + w * PW_STRIDE;
    float2 tmp[8];

    // phase D'
#pragma unroll
    for (int q = 0; q < 4; ++q) dft4<true>(x[4*q], x[4*q+1], x[4*q+2], x[4*q+3]);

    // ---- exchange D' (diagonal mirror of C) ----
    {
        const int row = (kb & 7) * 68;
        const bool klo = (kb < 8);
        LGKM();   // ensure fwd phase-C reads fully drained before overwrite
        if (klo) {
#pragma unroll
            for (int q = 0; q < 4; ++q)
#pragma unroll
                for (int ff = 0; ff < 4; ++ff)
                    PW[row + CHI(f * 16 + q * 4 + ff)] = x[q * 4 + ff];
        }
        LGKM();
        if (klo) {
#pragma unroll
            for (int r = 0; r < 16; ++r) x[r] = PW[row + CHI(r * 4 + f)];
        }
        LGKM();
        if (!klo) {
#pragma unroll
            for (int q = 0; q < 4; ++q)
#pragma unroll
                for (int ff = 0; ff < 4; ++ff)
                    PW[row + CHI(f * 16 + q * 4 + ff)] = x[q * 4 + ff];
        }
        LGKM();
        if (!klo) {
#pragma unroll
            for (int r = 0; r < 16; ++r) x[r] = PW[row + CHI(r * 4 + f)];
        }
    }

    // phase C'
    twiddle_apply(x, TWO_PI * (float)f * (1.0f / 64.0f));
    dft16<true, false>(x);

    // ---- exchange C'->B' (intra-wave): write row kb col e*4+f, read row r col d
    // row-split by writer kb; slot = (row&7)*68 + CHI(col)
    {
        const int row = (kb & 7) * 68;
        const bool klo = (kb < 8);
        LGKM();
        if (klo) {
#pragma unroll
            for (int e = 0; e < 16; ++e) PW[row + CHI(e * 4 + f)] = x[e];
        }
        LGKM();
#pragma unroll
        for (int r = 0; r < 8; ++r) {
            float2 v = PW[r * 68 + CHI(d)];
            if (klo) x[r] = v; else tmp[r] = v;
        }
        LGKM();
        if (!klo) {
#pragma unroll
            for (int e = 0; e < 16; ++e) PW[row + CHI(e * 4 + f)] = x[e];
        }
        LGKM();
#pragma unroll
        for (int r = 8; r < 16; ++r) x[r] = PW[(r - 8) * 68 + CHI(d)];
        if (!klo) {
#pragma unroll
            for (int r = 0; r < 8; ++r) x[r] = tmp[r];
        }
    }

    // phase B'
    twiddle_apply(x, TWO_PI * (float)d * (1.0f / 1024.0f));
    dft16<true, false>(x);

    // ---- exchange B'->A': write p = w*1024 + c*64 + d, read p = r*1024 + t
    // row-split by writer wave through SH[0..8191]
    __syncthreads();   // all waves done with private-slice reads
    if (w < 8) {
#pragma unroll
        for (int c = 0; c < 16; ++c) SH[w * 1024 + c * 64 + d] = x[c];
    }
    __syncthreads();
#pragma unroll
    for (int r = 0; r < 8; ++r) {
        float2 v = SH[r * 1024 + t];
        if (w < 8) x[r] = v; else tmp[r] = v;
    }
    __syncthreads();
    if (w >= 8) {
#pragma unroll
        for (int c = 0; c < 16; ++c) SH[(w - 8) * 1024 + c * 64 + d] = x[c];
    }
    __syncthreads();
#pragma unroll
    for (int r = 8; r < 16; ++r) x[r] = SH[(r - 8) * 1024 + t];
    if (w >= 8) {
#pragma unroll
        for (int r = 0; r < 8; ++r) x[r] = tmp[r];
    }

    // phase A'
    twiddle_apply(x, TWO_PI * (float)t * (1.0f / 16384.0f));
    dft16<true, false>(x);
}

// ---------------- k0: W fp32 -> bf16 ----------------------------------------
__global__ void wconv(const float* __restrict__ W, ushort_t* __restrict__ Wb, int n)
{
    int i = blockIdx.x * 256 + threadIdx.x;
    if (i < n) Wb[i] = f2bf(W[i]);
}

// ---------------- k1: Kf[h][sigma] = FFT(k[h]) + D[h] -----------------------
__global__ __launch_bounds__(1024, 1) void kf_build(const float* __restrict__ k,
                                                    const float* __restrict__ D,
                                                    float2* __restrict__ Kf)
{
    __shared__ float2 SH[SH_SIZE];   // 73,728 B
    int h = blockIdx.x, t = threadIdx.x;
    const float* kr = k + (size_t)h * 8192;
    float2 x[16];
#pragma unroll
    for (int a = 0; a < 8; ++a) x[a] = make_float2(kr[a * 1024 + t], 0.f);
#pragma unroll
    for (int a = 8; a < 16; ++a) x[a] = make_float2(0.f, 0.f);
    fft_fwd(x, SH, t);
    float dh = D[h];
    float2* o = Kf + (size_t)h * 16384;
#pragma unroll
    for (int r = 0; r < 16; ++r) {
        float2 z = x[r];
        z.x += dh;                       // FFT(D*delta) = D on every bin
        o[r * 1024 + t] = z;
    }
}

// ---------------- k2: conv + D-skip + GELU -> g bf16 ------------------------
__global__ __launch_bounds__(1024, 1) void conv_gelu(const float* __restrict__ u,
                                                     const float2* __restrict__ Kf,
                                                     ushort_t* __restrict__ g)
{
    __shared__ float2 SH[SH_SIZE];   // 73,728 B
    int h    = blockIdx.x;         // 512
    int pair = blockIdx.y;         // 4
    int b0   = pair * 2;
    int t    = threadIdx.x;
    const float* u0 = u + ((size_t)(b0 * 512 + h)) * 8192;
    const float* u1 = u0 + (size_t)512 * 8192;
    float2 x[16];
#pragma unroll
    for (int a = 0; a < 8; ++a) x[a] = make_float2(u0[a * 1024 + t], u1[a * 1024 + t]);
#pragma unroll
    for (int a = 8; a < 16; ++a) x[a] = make_float2(0.f, 0.f);
    fft_fwd(x, SH, t);
    const float2* kf = Kf + (size_t)blockIdx.x * 16384;
#pragma unroll
    for (int r = 0; r < 16; ++r) x[r] = cmulf(x[r], kf[r * 1024 + t]);
    fft_inv(x, SH, t);
    const float sc = 1.0f / 16384.0f;
    ushort_t* g0 = g + ((size_t)(b0 * 512 + blockIdx.x)) * 8192;
    ushort_t* g1 = g0 + (size_t)512 * 8192;
#pragma unroll
    for (int a = 0; a < 8; ++a) {
        int n = a * 1024 + t;
        g0[n] = f2bf(gelu_exact(x[a].x * sc));   // batch b0
        g1[n] = f2bf(gelu_exact(x[a].y * sc));   // batch b0+1
    }
}

// ---------------- kT: g[b][h][l] -> gT[b][l][h] -----------------------------
__global__ __launch_bounds__(256) void transpose_g(const ushort_t* __restrict__ g,
                                                   ushort_t* __restrict__ gT)
{
    __shared__ ushort_t TL[64][68];   // [l][h], padded
    int lt = blockIdx.x;   // 128 l-tiles of 64
    int ht = blockIdx.y;   // 8 h-tiles of 64
    int b  = blockIdx.z;   // 8
    int t  = threadIdx.x;
    int l0 = lt * 64, h0 = ht * 64;
#pragma unroll
    for (int i = 0; i < 4; ++i) {
        int c   = t + (i << 8);        // 0..1023 ushort4-chunks
        int row = c >> 4;              // h-row 0..63
        int col = (c & 15) * 4;        // l-col
        const ushort_t* src = g + ((size_t)(b * 512 + h0 + row)) * 8192 + l0 + col;
        ushort4 v = *(const ushort4*)src;
        TL[col + 0][row] = v.x;
        TL[col + 1][row] = v.y;
        TL[col + 2][row] = v.z;
        TL[col + 3][row] = v.w;
    }
    __syncthreads();
#pragma unroll
    for (int i = 0; i < 4; ++i) {
        int c    = t + (i << 8);
        int lrow = c >> 4;
        int hcol = (c & 15) * 4;
        ushort4 v = *(const ushort4*)&TL[lrow][hcol];
        *(ushort4*)(gT + ((size_t)b * 8192 + l0 + lrow) * 512 + h0 + hcol) = v;
    }
}

// ---------------- k3: out[b,o,l] = sum_d Wb[o,d]*gT[b,l,d] + bias[o] --------
__global__ __launch_bounds__(256, 2) void gemm_out(const ushort_t* __restrict__ Wb,
                                                   const ushort_t* __restrict__ gT,
                                                   const float* __restrict__ bias,
                                                   float* __restrict__ out)
{
    __shared__ __align__(16) ushort_t As[128 * 32];  // [o][k]
    __shared__ __align__(16) ushort_t Bs[128 * 32];  // [l][k]
    int lt = blockIdx.x;   // 64 l-tiles
    int ot = blockIdx.y;   // 4 o-tiles
    int b  = blockIdx.z;   // 8
    int l0 = lt * 128, o0 = ot * 128;
    int t    = threadIdx.x;
    int wave = t >> 6, lid = t & 63;
    int wm = wave >> 1, wn = wave & 1;
    int q  = lid >> 4, mi = lid & 15;

    f32x4 acc[4][4];
#pragma unroll
    for (int i = 0; i < 4; ++i)
#pragma unroll
        for (int j = 0; j < 4; ++j)
            acc[i][j] = (f32x4){0.f, 0.f, 0.f, 0.f};

    const size_t gTb = (size_t)b * 8192 * 512;
    for (int it = 0; it < 16; ++it) {
        int k0 = it * 32;
        __syncthreads();
#pragma unroll
        for (int i = 0; i < 2; ++i) {
            int ch  = t + (i << 8);          // 0..511 16B-chunks
            int row = ch >> 2;
            int kc  = (ch & 3) << 3;
            uint4 va = *(const uint4*)(Wb + (size_t)(o0 + row) * 512 + k0 + kc);
            *(uint4*)&As[row * 32 + kc] = va;
            uint4 vb = *(const uint4*)(gT + gTb + (size_t)(l0 + row) * 512 + k0 + kc);
            *(uint4*)&Bs[row * 32 + kc] = vb;
        }
        __syncthreads();
        bf16x8 af[4], bfr[4];
#pragma unroll
        for (int ff = 0; ff < 4; ++ff) {
            af[ff]  = *(const bf16x8*)&As[(wm * 64 + ff * 16 + mi) * 32 + q * 8];
            bfr[ff] = *(const bf16x8*)&Bs[(wn * 64 + ff * 16 + mi) * 32 + q * 8];
        }
#pragma unroll
        for (int i = 0; i < 4; ++i)
#pragma unroll
            for (int j = 0; j < 4; ++j)
                acc[i][j] = __builtin_amdgcn_mfma_f32_16x16x32_bf16(af[i], bfr[j], acc[i][j], 0, 0, 0);
    }

#pragma unroll
    for (int i = 0; i < 4; ++i) {
        int o_base = o0 + wm * 64 + i * 16 + q * 4;
#pragma unroll
        for (int j = 0; j < 4; ++j) {
            int l = l0 + wn * 64 + j * 16 + mi;
#pragma unroll
            for (int r = 0; r < 4; ++r) {
                int o = o_base + r;
                out[((size_t)b * 512 + o) * 8192 + l] = acc[i][j][r] + bias[o];
            }
        }
    }
}

// ----------------------------------------------------------------------------
extern "C" void kernel_launch(void* const* d_in, const int* in_sizes, int n_in,
                              void* d_out, int out_size, void* d_ws, size_t ws_size,
                              hipStream_t stream)
{
    (void)in_sizes; (void)n_in; (void)out_size; (void)ws_size;
    const float* u    = (const float*)d_in[0];   // (8,512,8192)
    const float* k    = (const float*)d_in[1];   // (1,512,8192)
    const float* D    = (const float*)d_in[2];   // (1,512)
    const float* W    = (const float*)d_in[3];   // (512,512)
    const float* bias = (const float*)d_in[4];   // (512,)
    float* out = (float*)d_out;

    char* ws = (char*)d_ws;
    float2*   Kf = (float2*)ws;                          // 512*16384*8 = 64 MB
    ushort_t* gT = (ushort_t*)(ws + 67108864);           // 64 MB
    ushort_t* Wb = (ushort_t*)(ws + 134217728);          // 512 KB
    ushort_t* g  = (ushort_t*)d_out;                     // 64 MB staged in out buf

    wconv<<<1024, 256, 0, stream>>>(W, Wb, 512 * 512);
    kf_build<<<512, 1024, 0, stream>>>(k, D, Kf);
    conv_gelu<<<dim3(512, 4), 1024, 0, stream>>>(u, Kf, g);
    transpose_g<<<dim3(128, 8, 8), 256, 0, stream>>>(g, gT);
    gemm_out<<<dim3(64, 4, 8), 256, 0, stream>>>(Wb, gT, bias, out);
}